// Round 3
// baseline (581.147 us; speedup 1.0000x reference)
//
#include <hip/hip_runtime.h>

#define D 64

// --- degree histogram over dst (4 edges/thread, int4 loads) ----------------
__global__ void count_deg_kernel(const int* __restrict__ dst, int* __restrict__ deg, int nE) {
    int e4 = (blockIdx.x * blockDim.x + threadIdx.x) * 4;
    if (e4 + 3 < nE) {
        int4 d = *(const int4*)(dst + e4);
        atomicAdd(&deg[d.x], 1);
        atomicAdd(&deg[d.y], 1);
        atomicAdd(&deg[d.z], 1);
        atomicAdd(&deg[d.w], 1);
    } else {
        for (int e = e4; e < nE; ++e) atomicAdd(&deg[dst[e]], 1);
    }
}

// --- hierarchical exclusive scan: A (per-block tile scan) ------------------
__global__ __launch_bounds__(256) void scan_a_kernel(const int* __restrict__ deg,
                                                     int* __restrict__ row_ptr,
                                                     int* __restrict__ blocksums, int N) {
    __shared__ int s[256];
    int t = threadIdx.x;
    int i = blockIdx.x * 256 + t;
    int v = (i < N) ? deg[i] : 0;
    s[t] = v;
    __syncthreads();
    #pragma unroll
    for (int d = 1; d < 256; d <<= 1) {
        int u = (t >= d) ? s[t - d] : 0;
        __syncthreads();
        s[t] += u;
        __syncthreads();
    }
    if (i < N) row_ptr[i] = s[t] - v;             // exclusive (block-local)
    if (t == 255) blocksums[blockIdx.x] = s[255]; // block total
}

// --- B: single-block exclusive scan of block sums (nb <= 256) --------------
__global__ __launch_bounds__(256) void scan_b_kernel(int* __restrict__ blocksums,
                                                     int* __restrict__ row_ptr,
                                                     int nb, int N) {
    __shared__ int s[256];
    int t = threadIdx.x;
    int v = (t < nb) ? blocksums[t] : 0;
    s[t] = v;
    __syncthreads();
    #pragma unroll
    for (int d = 1; d < 256; d <<= 1) {
        int u = (t >= d) ? s[t - d] : 0;
        __syncthreads();
        s[t] += u;
        __syncthreads();
    }
    if (t < nb) blocksums[t] = s[t] - v;  // exclusive block offsets
    if (t == 255) row_ptr[N] = s[255];    // total = E
}

// --- C: apply block offsets, emit final row_ptr + cursor -------------------
__global__ __launch_bounds__(256) void scan_c_kernel(int* __restrict__ row_ptr,
                                                     int* __restrict__ cursor,
                                                     const int* __restrict__ blocksums, int N) {
    int i = blockIdx.x * 256 + threadIdx.x;
    if (i < N) {
        int r = row_ptr[i] + blocksums[blockIdx.x];
        row_ptr[i] = r;
        cursor[i] = r;
    }
}

// --- bucket edges by dst: col[pos] = src, dst-sliced for XCD locality ------
__global__ __launch_bounds__(256) void fill_csr_sliced_kernel(
    const int* __restrict__ src, const int* __restrict__ dst,
    int* __restrict__ cursor, int* __restrict__ col,
    int nE, int slice_size)
{
    const int g  = blockIdx.x & 7;    // slice id == XCD id (perf heuristic)
    const int gb = blockIdx.x >> 3;   // block index within group
    const int lo = g * slice_size;
    const int hi = lo + slice_size;
    int e4 = (gb * 256 + (int)threadIdx.x) * 4;
    if (e4 + 3 < nE) {
        int4 d = *(const int4*)(dst + e4);
        bool m0 = (d.x >= lo) & (d.x < hi);
        bool m1 = (d.y >= lo) & (d.y < hi);
        bool m2 = (d.z >= lo) & (d.z < hi);
        bool m3 = (d.w >= lo) & (d.w < hi);
        if (m0 | m1 | m2 | m3) {
            int4 s = *(const int4*)(src + e4);
            if (m0) col[atomicAdd(&cursor[d.x], 1)] = s.x;
            if (m1) col[atomicAdd(&cursor[d.y], 1)] = s.y;
            if (m2) col[atomicAdd(&cursor[d.z], 1)] = s.z;
            if (m3) col[atomicAdd(&cursor[d.w], 1)] = s.w;
        }
    } else if (e4 < nE) {
        for (int e = e4; e < nE; ++e) {
            int dd = dst[e];
            if (dd >= lo && dd < hi) col[atomicAdd(&cursor[dd], 1)] = src[e];
        }
    }
}

// --- fused layer: out = relu?( ((sum_{s in N(i)} h[s] + h[i]) / (deg+1)) @ W + b )
// One wave per node, zero barriers in the node loop.
// This is the ROUND-0 body (proven: 60 arch VGPRs, zero scratch) with exactly
// two changes:
//  * W in LDS instead of Wreg[64]-in-AGPR. Round 0's 60 VGPR + 64 AGPR = 124
//    unified regs -> 128-granule -> 4 waves/EU (occupancy 34%). Dropping the
//    AGPR array -> ~60 total -> 64-granule -> 8 waves/EU. launch_bounds(256,8)
//    is now CONSISTENT with the live set (round 2 capped a bigger body at 64
//    and the spiller evicted the accumulators: 200MB scratch writes, 3x slower).
//  * pad-row index via __shfl(last_iv,63) instead of dependent col[re-1]
//    reload (hits 75% of nodes; +1 register).
// NO cross-node software pipeline (round 1/2 lesson: its +8 live regs is what
// broke the register budget; at 8 waves/EU, TLP hides the per-node stalls).
__global__ __launch_bounds__(256, 8) void sage_layer_kernel(
    const float* __restrict__ h, const int* __restrict__ row_ptr,
    const int* __restrict__ col, const float* __restrict__ W,
    const float* __restrict__ bias, float* __restrict__ out,
    int N, int do_relu)
{
    __shared__ float Wlds[D * D];
    {
        const float4* W4 = (const float4*)W;
        float4* Wl4 = (float4*)Wlds;
        #pragma unroll
        for (int t = 0; t < 4; ++t)
            Wl4[t * 256 + threadIdx.x] = W4[t * 256 + threadIdx.x];
    }
    __syncthreads();

    const int lane = threadIdx.x & 63;
    const int sub  = lane >> 4;       // edge subgroup 0..3
    const int fq   = lane & 15;       // feature quad (features 4*fq..4*fq+3)
    const int w    = threadIdx.x >> 6;
    const float bj = bias[lane];

    const float4* __restrict__ h4 = (const float4*)h;   // row i = h4[i*16 + fq]

    const int nwaves = gridDim.x * 4;
    for (int i0 = blockIdx.x * 4 + w; i0 < N; i0 += nwaves) {
        const int i   = __builtin_amdgcn_readfirstlane(i0);
        const int rs  = __builtin_amdgcn_readfirstlane(row_ptr[i]);
        const int re  = __builtin_amdgcn_readfirstlane(row_ptr[i + 1]);
        const int deg = re - rs;

        float4 a0 = {0,0,0,0}, a1 = {0,0,0,0}, a2 = {0,0,0,0}, a3 = {0,0,0,0};
        int last_iv = 0;

        for (int e0 = rs; e0 < re; e0 += 64) {
            int ee = e0 + lane;
            int idxv = col[(ee < re) ? ee : (re - 1)];   // 64 indices, coalesced
            last_iv = idxv;
            int rem = re - e0;                            // scalar
            int steps = (((rem < 64) ? rem : 64) + 3) >> 2;  // scalar 1..16
            int t = 0;
            for (; t + 4 <= steps; t += 4) {
                int base = (t << 2) + sub;
                int s0 = __shfl(idxv, base);
                int s1 = __shfl(idxv, base + 4);
                int s2 = __shfl(idxv, base + 8);
                int s3 = __shfl(idxv, base + 12);
                float4 v0 = h4[(size_t)s0 * 16 + fq];
                float4 v1 = h4[(size_t)s1 * 16 + fq];
                float4 v2 = h4[(size_t)s2 * 16 + fq];
                float4 v3 = h4[(size_t)s3 * 16 + fq];
                a0.x += v0.x; a0.y += v0.y; a0.z += v0.z; a0.w += v0.w;
                a1.x += v1.x; a1.y += v1.y; a1.z += v1.z; a1.w += v1.w;
                a2.x += v2.x; a2.y += v2.y; a2.z += v2.z; a2.w += v2.w;
                a3.x += v3.x; a3.y += v3.y; a3.z += v3.z; a3.w += v3.w;
            }
            for (; t < steps; ++t) {
                int s0 = __shfl(idxv, (t << 2) + sub);
                float4 v0 = h4[(size_t)s0 * 16 + fq];
                a0.x += v0.x; a0.y += v0.y; a0.z += v0.z; a0.w += v0.w;
            }
        }

        // combine step accumulators
        float4 tt;
        tt.x = (a0.x + a1.x) + (a2.x + a3.x);
        tt.y = (a0.y + a1.y) + (a2.y + a3.y);
        tt.z = (a0.z + a1.z) + (a2.z + a3.z);
        tt.w = (a0.w + a1.w) + (a2.w + a3.w);
        // reduce across the 4 edge subgroups (lanes l, l^16, l^32, l^48)
        tt.x += __shfl_xor(tt.x, 16); tt.x += __shfl_xor(tt.x, 32);
        tt.y += __shfl_xor(tt.y, 16); tt.y += __shfl_xor(tt.y, 32);
        tt.z += __shfl_xor(tt.z, 16); tt.z += __shfl_xor(tt.z, 32);
        tt.w += __shfl_xor(tt.w, 16); tt.w += __shfl_xor(tt.w, 32);

        // pad correction: clamped lanes duplicated col[re-1] `pad` times.
        // pad>0 => deg%4!=0 => last chunk had rem<64 => its lane 63 was clamped
        // to re-1, so last_iv lane 63 holds col[re-1]: shfl, no reload.
        int pad = (-deg) & 3;
        if (deg > 0 && pad) {
            int last = __shfl(last_iv, 63);
            float4 vl = h4[(size_t)last * 16 + fq];
            float fp = (float)pad;
            tt.x = fmaf(-fp, vl.x, tt.x);
            tt.y = fmaf(-fp, vl.y, tt.y);
            tt.z = fmaf(-fp, vl.z, tt.z);
            tt.w = fmaf(-fp, vl.w, tt.w);
        }

        // self term + normalize
        float4 hs = h4[(size_t)i * 16 + fq];
        float invd = 1.0f / (float)(deg + 1);
        tt.x = (tt.x + hs.x) * invd;
        tt.y = (tt.y + hs.y) * invd;
        tt.z = (tt.z + hs.z) * invd;
        tt.w = (tt.w + hs.w) * invd;

        // GEMM: o[lane] = bj + sum_k t[k] * W[k][lane]; W from LDS.
        // Bank: (k*64+lane)%32 = lane%32 -> 2-way across the wave = free.
        float o0 = bj, o1 = 0.0f, o2 = 0.0f, o3 = 0.0f;
        #pragma unroll
        for (int k = 0; k < D; k += 4) {
            const int q = k >> 2;   // source lane holding features k..k+3
            int t0 = __builtin_amdgcn_readlane(__float_as_int(tt.x), q);
            int t1 = __builtin_amdgcn_readlane(__float_as_int(tt.y), q);
            int t2 = __builtin_amdgcn_readlane(__float_as_int(tt.z), q);
            int t3 = __builtin_amdgcn_readlane(__float_as_int(tt.w), q);
            o0 = fmaf(__int_as_float(t0), Wlds[(k + 0) * D + lane], o0);
            o1 = fmaf(__int_as_float(t1), Wlds[(k + 1) * D + lane], o1);
            o2 = fmaf(__int_as_float(t2), Wlds[(k + 2) * D + lane], o2);
            o3 = fmaf(__int_as_float(t3), Wlds[(k + 3) * D + lane], o3);
        }
        float o = (o0 + o1) + (o2 + o3);
        if (do_relu) o = fmaxf(o, 0.0f);
        out[(size_t)i * D + lane] = o;
    }
}

extern "C" void kernel_launch(void* const* d_in, const int* in_sizes, int n_in,
                              void* d_out, int out_size, void* d_ws, size_t ws_size,
                              hipStream_t stream) {
    const float* x   = (const float*)d_in[0];
    const int*   src = (const int*)d_in[1];
    const int*   dst = (const int*)d_in[2];
    const float* W0  = (const float*)d_in[3];
    const float* b0  = (const float*)d_in[4];
    const float* W1  = (const float*)d_in[5];
    const float* b1  = (const float*)d_in[6];
    const float* W2  = (const float*)d_in[7];
    const float* b2  = (const float*)d_in[8];
    float* out = (float*)d_out;

    const int N = in_sizes[0] / D;   // 50000
    const int E = in_sizes[1];       // 800000

    const int scan_blocks = (N + 255) / 256;  // 196 (<= 256 required by scan_b)

    // workspace: deg | row_ptr | cursor | blocksums | col | h1 | h2
    char* ws = (char*)d_ws;
    size_t off = 0;
    auto alloc = [&](size_t bytes) -> void* {
        void* p = ws + off;
        off = (off + bytes + 255) & ~(size_t)255;
        return p;
    };
    int*   deg       = (int*)  alloc((size_t)N * sizeof(int));
    int*   row_ptr   = (int*)  alloc((size_t)(N + 1) * sizeof(int));
    int*   cursor    = (int*)  alloc((size_t)N * sizeof(int));
    int*   blocksums = (int*)  alloc((size_t)scan_blocks * sizeof(int));
    int*   col       = (int*)  alloc((size_t)E * sizeof(int));
    float* h1        = (float*)alloc((size_t)N * D * sizeof(float));
    float* h2        = (float*)alloc((size_t)N * D * sizeof(float));

    // --- build CSR (once per call; reused by all 3 layers) ---
    hipMemsetAsync(deg, 0, (size_t)N * sizeof(int), stream);
    const int e4_blocks = (E / 4 + 255) / 256;  // 782
    count_deg_kernel<<<e4_blocks, 256, 0, stream>>>(dst, deg, E);
    scan_a_kernel<<<scan_blocks, 256, 0, stream>>>(deg, row_ptr, blocksums, N);
    scan_b_kernel<<<1, 256, 0, stream>>>(blocksums, row_ptr, scan_blocks, N);
    scan_c_kernel<<<scan_blocks, 256, 0, stream>>>(row_ptr, cursor, blocksums, N);
    const int slice_size = (N + 7) / 8;         // 6250
    fill_csr_sliced_kernel<<<e4_blocks * 8, 256, 0, stream>>>(src, dst, cursor, col, E, slice_size);

    const int layer_blocks = 4096;  // 16KB LDS + <=64 regs => 8 blocks/CU resident

    sage_layer_kernel<<<layer_blocks, 256, 0, stream>>>(x,  row_ptr, col, W0, b0, h1,  N, 1);
    sage_layer_kernel<<<layer_blocks, 256, 0, stream>>>(h1, row_ptr, col, W1, b1, h2,  N, 1);
    sage_layer_kernel<<<layer_blocks, 256, 0, stream>>>(h2, row_ptr, col, W2, b2, out, N, 0);
}

// Round 4
// 285.992 us; speedup vs baseline: 2.0320x; 2.0320x over previous
//
#include <hip/hip_runtime.h>

#define D 64

// --- degree histogram over dst (4 edges/thread, int4 loads) ----------------
__global__ void count_deg_kernel(const int* __restrict__ dst, int* __restrict__ deg, int nE) {
    int e4 = (blockIdx.x * blockDim.x + threadIdx.x) * 4;
    if (e4 + 3 < nE) {
        int4 d = *(const int4*)(dst + e4);
        atomicAdd(&deg[d.x], 1);
        atomicAdd(&deg[d.y], 1);
        atomicAdd(&deg[d.z], 1);
        atomicAdd(&deg[d.w], 1);
    } else {
        for (int e = e4; e < nE; ++e) atomicAdd(&deg[dst[e]], 1);
    }
}

// --- hierarchical exclusive scan: A (per-block tile scan) ------------------
__global__ __launch_bounds__(256) void scan_a_kernel(const int* __restrict__ deg,
                                                     int* __restrict__ row_ptr,
                                                     int* __restrict__ blocksums, int N) {
    __shared__ int s[256];
    int t = threadIdx.x;
    int i = blockIdx.x * 256 + t;
    int v = (i < N) ? deg[i] : 0;
    s[t] = v;
    __syncthreads();
    #pragma unroll
    for (int d = 1; d < 256; d <<= 1) {
        int u = (t >= d) ? s[t - d] : 0;
        __syncthreads();
        s[t] += u;
        __syncthreads();
    }
    if (i < N) row_ptr[i] = s[t] - v;             // exclusive (block-local)
    if (t == 255) blocksums[blockIdx.x] = s[255]; // block total
}

// --- B: single-block exclusive scan of block sums (nb <= 256) --------------
__global__ __launch_bounds__(256) void scan_b_kernel(int* __restrict__ blocksums,
                                                     int* __restrict__ row_ptr,
                                                     int nb, int N) {
    __shared__ int s[256];
    int t = threadIdx.x;
    int v = (t < nb) ? blocksums[t] : 0;
    s[t] = v;
    __syncthreads();
    #pragma unroll
    for (int d = 1; d < 256; d <<= 1) {
        int u = (t >= d) ? s[t - d] : 0;
        __syncthreads();
        s[t] += u;
        __syncthreads();
    }
    if (t < nb) blocksums[t] = s[t] - v;  // exclusive block offsets
    if (t == 255) row_ptr[N] = s[255];    // total = E
}

// --- C: apply block offsets, emit final row_ptr + cursor -------------------
__global__ __launch_bounds__(256) void scan_c_kernel(int* __restrict__ row_ptr,
                                                     int* __restrict__ cursor,
                                                     const int* __restrict__ blocksums, int N) {
    int i = blockIdx.x * 256 + threadIdx.x;
    if (i < N) {
        int r = row_ptr[i] + blocksums[blockIdx.x];
        row_ptr[i] = r;
        cursor[i] = r;
    }
}

// --- bucket edges by dst: col[pos] = src, dst-sliced for XCD locality ------
__global__ __launch_bounds__(256) void fill_csr_sliced_kernel(
    const int* __restrict__ src, const int* __restrict__ dst,
    int* __restrict__ cursor, int* __restrict__ col,
    int nE, int slice_size)
{
    const int g  = blockIdx.x & 7;    // slice id == XCD id (perf heuristic)
    const int gb = blockIdx.x >> 3;   // block index within group
    const int lo = g * slice_size;
    const int hi = lo + slice_size;
    int e4 = (gb * 256 + (int)threadIdx.x) * 4;
    if (e4 + 3 < nE) {
        int4 d = *(const int4*)(dst + e4);
        bool m0 = (d.x >= lo) & (d.x < hi);
        bool m1 = (d.y >= lo) & (d.y < hi);
        bool m2 = (d.z >= lo) & (d.z < hi);
        bool m3 = (d.w >= lo) & (d.w < hi);
        if (m0 | m1 | m2 | m3) {
            int4 s = *(const int4*)(src + e4);
            if (m0) col[atomicAdd(&cursor[d.x], 1)] = s.x;
            if (m1) col[atomicAdd(&cursor[d.y], 1)] = s.y;
            if (m2) col[atomicAdd(&cursor[d.z], 1)] = s.z;
            if (m3) col[atomicAdd(&cursor[d.w], 1)] = s.w;
        }
    } else if (e4 < nE) {
        for (int e = e4; e < nE; ++e) {
            int dd = dst[e];
            if (dd >= lo && dd < hi) col[atomicAdd(&cursor[dd], 1)] = src[e];
        }
    }
}

// --- fused layer: out = relu?( ((sum_{s in N(i)} h[s] + h[i]) / (deg+1)) @ W + b )
// One wave per node, zero barriers in the node loop.
// ROUND-0 body verbatim (proven: 60 arch VGPRs, zero scratch) with two changes:
//  * W in LDS instead of Wreg[64]-in-AGPR: round 0 was 60 VGPR + 64 AGPR = 124
//    unified regs -> 4 waves/EU. Same body w/o the AGPR array should land
//    ~60-80 regs -> 6-8 waves/EU.
//  * pad-row index via __shfl(last_iv,63) (no dependent col[re-1] reload).
// CRITICAL: launch_bounds min-waves stays at 4. Rounds 1-3 proved that forcing
// 8 waves/EU (64-reg cap) on this body makes the spiller demote the in-flight
// gather values to scratch: WRITE_SIZE ballooned to exactly the gathered
// volume (205 MB) and the kernel ran 3x slower. Occupancy must come from the
// allocator landing low naturally, never from a cap below the live set.
__global__ __launch_bounds__(256, 4) void sage_layer_kernel(
    const float* __restrict__ h, const int* __restrict__ row_ptr,
    const int* __restrict__ col, const float* __restrict__ W,
    const float* __restrict__ bias, float* __restrict__ out,
    int N, int do_relu)
{
    __shared__ float Wlds[D * D];
    {
        const float4* W4 = (const float4*)W;
        float4* Wl4 = (float4*)Wlds;
        #pragma unroll
        for (int t = 0; t < 4; ++t)
            Wl4[t * 256 + threadIdx.x] = W4[t * 256 + threadIdx.x];
    }
    __syncthreads();

    const int lane = threadIdx.x & 63;
    const int sub  = lane >> 4;       // edge subgroup 0..3
    const int fq   = lane & 15;       // feature quad (features 4*fq..4*fq+3)
    const int w    = threadIdx.x >> 6;
    const float bj = bias[lane];

    const float4* __restrict__ h4 = (const float4*)h;   // row i = h4[i*16 + fq]

    const int nwaves = gridDim.x * 4;
    for (int i0 = blockIdx.x * 4 + w; i0 < N; i0 += nwaves) {
        const int i   = __builtin_amdgcn_readfirstlane(i0);
        const int rs  = __builtin_amdgcn_readfirstlane(row_ptr[i]);
        const int re  = __builtin_amdgcn_readfirstlane(row_ptr[i + 1]);
        const int deg = re - rs;

        float4 a0 = {0,0,0,0}, a1 = {0,0,0,0}, a2 = {0,0,0,0}, a3 = {0,0,0,0};
        int last_iv = 0;

        for (int e0 = rs; e0 < re; e0 += 64) {
            int ee = e0 + lane;
            int idxv = col[(ee < re) ? ee : (re - 1)];   // 64 indices, coalesced
            last_iv = idxv;
            int rem = re - e0;                            // scalar
            int steps = (((rem < 64) ? rem : 64) + 3) >> 2;  // scalar 1..16
            int t = 0;
            for (; t + 4 <= steps; t += 4) {
                int base = (t << 2) + sub;
                int s0 = __shfl(idxv, base);
                int s1 = __shfl(idxv, base + 4);
                int s2 = __shfl(idxv, base + 8);
                int s3 = __shfl(idxv, base + 12);
                float4 v0 = h4[(size_t)s0 * 16 + fq];
                float4 v1 = h4[(size_t)s1 * 16 + fq];
                float4 v2 = h4[(size_t)s2 * 16 + fq];
                float4 v3 = h4[(size_t)s3 * 16 + fq];
                a0.x += v0.x; a0.y += v0.y; a0.z += v0.z; a0.w += v0.w;
                a1.x += v1.x; a1.y += v1.y; a1.z += v1.z; a1.w += v1.w;
                a2.x += v2.x; a2.y += v2.y; a2.z += v2.z; a2.w += v2.w;
                a3.x += v3.x; a3.y += v3.y; a3.z += v3.z; a3.w += v3.w;
            }
            for (; t < steps; ++t) {
                int s0 = __shfl(idxv, (t << 2) + sub);
                float4 v0 = h4[(size_t)s0 * 16 + fq];
                a0.x += v0.x; a0.y += v0.y; a0.z += v0.z; a0.w += v0.w;
            }
        }

        // combine step accumulators
        float4 tt;
        tt.x = (a0.x + a1.x) + (a2.x + a3.x);
        tt.y = (a0.y + a1.y) + (a2.y + a3.y);
        tt.z = (a0.z + a1.z) + (a2.z + a3.z);
        tt.w = (a0.w + a1.w) + (a2.w + a3.w);
        // reduce across the 4 edge subgroups (lanes l, l^16, l^32, l^48)
        tt.x += __shfl_xor(tt.x, 16); tt.x += __shfl_xor(tt.x, 32);
        tt.y += __shfl_xor(tt.y, 16); tt.y += __shfl_xor(tt.y, 32);
        tt.z += __shfl_xor(tt.z, 16); tt.z += __shfl_xor(tt.z, 32);
        tt.w += __shfl_xor(tt.w, 16); tt.w += __shfl_xor(tt.w, 32);

        // pad correction: clamped lanes duplicated col[re-1] `pad` times.
        // pad>0 => deg%4!=0 => last chunk had rem<64 => its lane 63 was clamped
        // to re-1, so last_iv lane 63 holds col[re-1]: shfl, no reload.
        int pad = (-deg) & 3;
        if (deg > 0 && pad) {
            int last = __shfl(last_iv, 63);
            float4 vl = h4[(size_t)last * 16 + fq];
            float fp = (float)pad;
            tt.x = fmaf(-fp, vl.x, tt.x);
            tt.y = fmaf(-fp, vl.y, tt.y);
            tt.z = fmaf(-fp, vl.z, tt.z);
            tt.w = fmaf(-fp, vl.w, tt.w);
        }

        // self term + normalize
        float4 hs = h4[(size_t)i * 16 + fq];
        float invd = 1.0f / (float)(deg + 1);
        tt.x = (tt.x + hs.x) * invd;
        tt.y = (tt.y + hs.y) * invd;
        tt.z = (tt.z + hs.z) * invd;
        tt.w = (tt.w + hs.w) * invd;

        // GEMM: o[lane] = bj + sum_k t[k] * W[k][lane]; W from LDS.
        // Bank: (k*64+lane)%32 = lane%32 -> 2-way across the wave = free.
        float o0 = bj, o1 = 0.0f, o2 = 0.0f, o3 = 0.0f;
        #pragma unroll
        for (int k = 0; k < D; k += 4) {
            const int q = k >> 2;   // source lane holding features k..k+3
            int t0 = __builtin_amdgcn_readlane(__float_as_int(tt.x), q);
            int t1 = __builtin_amdgcn_readlane(__float_as_int(tt.y), q);
            int t2 = __builtin_amdgcn_readlane(__float_as_int(tt.z), q);
            int t3 = __builtin_amdgcn_readlane(__float_as_int(tt.w), q);
            o0 = fmaf(__int_as_float(t0), Wlds[(k + 0) * D + lane], o0);
            o1 = fmaf(__int_as_float(t1), Wlds[(k + 1) * D + lane], o1);
            o2 = fmaf(__int_as_float(t2), Wlds[(k + 2) * D + lane], o2);
            o3 = fmaf(__int_as_float(t3), Wlds[(k + 3) * D + lane], o3);
        }
        float o = (o0 + o1) + (o2 + o3);
        if (do_relu) o = fmaxf(o, 0.0f);
        out[(size_t)i * D + lane] = o;
    }
}

extern "C" void kernel_launch(void* const* d_in, const int* in_sizes, int n_in,
                              void* d_out, int out_size, void* d_ws, size_t ws_size,
                              hipStream_t stream) {
    const float* x   = (const float*)d_in[0];
    const int*   src = (const int*)d_in[1];
    const int*   dst = (const int*)d_in[2];
    const float* W0  = (const float*)d_in[3];
    const float* b0  = (const float*)d_in[4];
    const float* W1  = (const float*)d_in[5];
    const float* b1  = (const float*)d_in[6];
    const float* W2  = (const float*)d_in[7];
    const float* b2  = (const float*)d_in[8];
    float* out = (float*)d_out;

    const int N = in_sizes[0] / D;   // 50000
    const int E = in_sizes[1];       // 800000

    const int scan_blocks = (N + 255) / 256;  // 196 (<= 256 required by scan_b)

    // workspace: deg | row_ptr | cursor | blocksums | col | h1 | h2
    char* ws = (char*)d_ws;
    size_t off = 0;
    auto alloc = [&](size_t bytes) -> void* {
        void* p = ws + off;
        off = (off + bytes + 255) & ~(size_t)255;
        return p;
    };
    int*   deg       = (int*)  alloc((size_t)N * sizeof(int));
    int*   row_ptr   = (int*)  alloc((size_t)(N + 1) * sizeof(int));
    int*   cursor    = (int*)  alloc((size_t)N * sizeof(int));
    int*   blocksums = (int*)  alloc((size_t)scan_blocks * sizeof(int));
    int*   col       = (int*)  alloc((size_t)E * sizeof(int));
    float* h1        = (float*)alloc((size_t)N * D * sizeof(float));
    float* h2        = (float*)alloc((size_t)N * D * sizeof(float));

    // --- build CSR (once per call; reused by all 3 layers) ---
    hipMemsetAsync(deg, 0, (size_t)N * sizeof(int), stream);
    const int e4_blocks = (E / 4 + 255) / 256;  // 782
    count_deg_kernel<<<e4_blocks, 256, 0, stream>>>(dst, deg, E);
    scan_a_kernel<<<scan_blocks, 256, 0, stream>>>(deg, row_ptr, blocksums, N);
    scan_b_kernel<<<1, 256, 0, stream>>>(blocksums, row_ptr, scan_blocks, N);
    scan_c_kernel<<<scan_blocks, 256, 0, stream>>>(row_ptr, cursor, blocksums, N);
    const int slice_size = (N + 7) / 8;         // 6250
    fill_csr_sliced_kernel<<<e4_blocks * 8, 256, 0, stream>>>(src, dst, cursor, col, E, slice_size);

    const int layer_blocks = 4096;

    sage_layer_kernel<<<layer_blocks, 256, 0, stream>>>(x,  row_ptr, col, W0, b0, h1,  N, 1);
    sage_layer_kernel<<<layer_blocks, 256, 0, stream>>>(h1, row_ptr, col, W1, b1, h2,  N, 1);
    sage_layer_kernel<<<layer_blocks, 256, 0, stream>>>(h2, row_ptr, col, W2, b2, out, N, 0);
}